// Round 4
// baseline (140.047 us; speedup 1.0000x reference)
//
#include <hip/hip_runtime.h>
#include <hip/hip_bf16.h>

// MarketEncoder collapses analytically:
//   feats = (feats - mean_t(feats)) / std_t(feats)   (standardize over time)
//   fmean = mean_t(feats) == 0 exactly  =>  h = bp for every batch row
//   => out[b,:] = b2 + W2 @ gelu_exact(W1 @ bp + b1)  broadcast over B=64 rows.
// Time-series inputs (close/high/low/open/volume) and Wp never affect the output.
// Confirmed R3: passed with absmax 1.22e-4 (threshold 7.28e-4).
//
// Dtypes (established R1-R3): inputs fp32, output fp32.
// Input order: 0=close 1=high 2=low 3=open_price 4=volume
//              5=Wp 6=bp 7=W1 8=b1 9=W2 10=b2
//
// R4 experiment: float4 loads + 4-way partial accumulators (ILP) to bound the
// kernel's own dispatch at ~2 us. If dur_us stays ~139 us, the window is
// harness-dominated (268 MB d_ws re-poison at 82% HBM peak + input restore)
// and we are at the floor we control.

#define ME_DIM 256
#define ME_HID 512
#define ME_B   64

__global__ __launch_bounds__(256) void market_encoder_const_kernel(
    const float4* __restrict__ bp4,   // [64]   = bp[256]
    const float4* __restrict__ W1_4,  // [512*64]  = W1[512,256] row-major
    const float*  __restrict__ b1,    // [512]
    const float4* __restrict__ W2_4,  // [256*128] = W2[256,512] row-major
    const float*  __restrict__ b2,    // [256]
    float* __restrict__ out)          // [64, 256] fp32
{
    __shared__ float4 s_bp[ME_DIM / 4];   // 256 floats
    __shared__ float4 s_g[ME_HID / 4];    // 512 floats

    const int tid = threadIdx.x;

    if (tid < ME_DIM / 4) s_bp[tid] = bp4[tid];
    __syncthreads();

    // Phase 1: each thread computes 2 hidden units g[j] = gelu_exact(b1[j] + W1[j,:]·bp)
    float g[2];
    #pragma unroll
    for (int r = 0; r < 2; ++r) {
        const int j = tid + r * ME_DIM;
        const float4* __restrict__ w = W1_4 + j * (ME_DIM / 4);
        float a0 = 0.f, a1 = 0.f, a2 = 0.f, a3 = 0.f;   // 4 independent chains
        #pragma unroll 8
        for (int k = 0; k < ME_DIM / 4; ++k) {
            const float4 wv = w[k];
            const float4 bv = s_bp[k];                   // all-lane LDS broadcast
            a0 += wv.x * bv.x; a1 += wv.y * bv.y;
            a2 += wv.z * bv.z; a3 += wv.w * bv.w;
        }
        const float z = b1[j] + ((a0 + a1) + (a2 + a3));
        // exact GELU (approximate=False): 0.5*x*(1+erf(x/sqrt(2)))
        g[r] = 0.5f * z * (1.0f + erff(z * 0.70710678118654752440f));
    }
    ((float*)s_g)[tid]          = g[0];
    ((float*)s_g)[tid + ME_DIM] = g[1];
    __syncthreads();

    // Phase 2: each thread computes one output dim: out_d = b2[d] + W2[d,:]·g
    const float4* __restrict__ w2 = W2_4 + tid * (ME_HID / 4);
    float a0 = 0.f, a1 = 0.f, a2 = 0.f, a3 = 0.f;
    #pragma unroll 8
    for (int j = 0; j < ME_HID / 4; ++j) {
        const float4 wv = w2[j];
        const float4 gv = s_g[j];                        // all-lane LDS broadcast
        a0 += wv.x * gv.x; a1 += wv.y * gv.y;
        a2 += wv.z * gv.z; a3 += wv.w * gv.w;
    }
    const float o = b2[tid] + ((a0 + a1) + (a2 + a3));

    // Block b writes batch row b (256 consecutive fp32 -> coalesced).
    out[blockIdx.x * ME_DIM + tid] = o;
}

extern "C" void kernel_launch(void* const* d_in, const int* in_sizes, int n_in,
                              void* d_out, int out_size, void* d_ws, size_t ws_size,
                              hipStream_t stream) {
    (void)in_sizes; (void)n_in; (void)out_size; (void)d_ws; (void)ws_size;

    const float4* bp4 = (const float4*)d_in[6];
    const float4* W1_4 = (const float4*)d_in[7];
    const float*  b1  = (const float*)d_in[8];
    const float4* W2_4 = (const float4*)d_in[9];
    const float*  b2  = (const float*)d_in[10];
    float* out = (float*)d_out;

    market_encoder_const_kernel<<<ME_B, 256, 0, stream>>>(bp4, W1_4, b1, W2_4, b2, out);
}